// Round 1
// baseline (1882.157 us; speedup 1.0000x reference)
//
#include <hip/hip_runtime.h>

// SearchTransfer on MI355X.
// B=2, C=16, H=W=96, k=3, pad=1, stride=1, lv=2 (sc=2 -> k2=6,p2=2,s2=2).
// L = 96*96 = 9216 patches/batch, KF = C*k*k = 144.
// out = [T_org (2*16*192*192 f32), S (2*9216, stored as f32 values)]

#define BATCH 2
#define CCH   16
#define HH    96
#define WW    96
#define LP    9216   // 96*96
#define KF    144    // 16*3*3
#define OH    192
#define OW    192

// ---------------------------------------------------------------- norms ----
// 1/max(||ref patch||, 1e-12) per (b, l). 144 reads each, coalesced over l.
__global__ void k_norm(const float* __restrict__ ref, float* __restrict__ rinv) {
    int gid = blockIdx.x * blockDim.x + threadIdx.x;
    if (gid >= BATCH * LP) return;
    int b = gid / LP, l = gid - b * LP;
    int py = l / WW, px = l - py * WW;
    const float* rb = ref + b * CCH * HH * WW;
    float s = 0.f;
    for (int c = 0; c < CCH; ++c) {
        const float* rc = rb + c * HH * WW;
        #pragma unroll
        for (int dy = 0; dy < 3; ++dy) {
            int y = py + dy - 1;
            if ((unsigned)y >= (unsigned)HH) continue;
            #pragma unroll
            for (int dx = 0; dx < 3; ++dx) {
                int x = px + dx - 1;
                if ((unsigned)x >= (unsigned)WW) continue;
                float v = rc[y * WW + x];
                s += v * v;
            }
        }
    }
    rinv[gid] = 1.f / fmaxf(sqrtf(s), 1e-12f);
}

// --------------------------------------------------------------- unfold ----
// Materialize refN (normalized) and lrU (raw; lr-normalization is a positive
// per-column scale -> argmax-invariant -> skipped) in [B][KF][LP] layout.
// gid order == output layout -> fully coalesced writes; reads coalesced in x.
__global__ void k_unfold(const float* __restrict__ lr, const float* __restrict__ ref,
                         const float* __restrict__ rinv,
                         float* __restrict__ refN, float* __restrict__ lrU) {
    int gid = blockIdx.x * blockDim.x + threadIdx.x;
    if (gid >= BATCH * KF * LP) return;
    int l = gid % LP;
    int t = gid / LP;
    int f = t % KF;
    int b = t / KF;
    int c = f / 9, r9 = f - c * 9;
    int dy = r9 / 3, dx = r9 - dy * 3;
    int py = l / WW, px = l - py * WW;
    int y = py + dy - 1, x = px + dx - 1;
    bool in = ((unsigned)y < (unsigned)HH) && ((unsigned)x < (unsigned)WW);
    int src = ((b * CCH + c) * HH + y) * WW + x;
    float rv = in ? ref[src] : 0.f;
    float lv = in ? lr[src]  : 0.f;
    refN[gid] = rv * rinv[b * LP + l];
    lrU[gid]  = lv;
}

// ------------------------------------------------------- GEMM + argmax -----
// Per block: 32 lr-columns, loop over 9216 ref rows in 64-row chunks.
// Thread layout tid = tc*16 + tr  (tr = lane%16): the argmax reduction over
// tr is a shfl_xor butterfly inside 16 consecutive lanes -> no LDS scratch.
// LDS K-major tiles: aT reads = 16 addrs on banks 4*tr -> 2-way (free);
// bT reads = 4 addrs/wave, distinct banks -> conflict-free.
__global__ __launch_bounds__(256) void k_gemm_argmax(
        const float* __restrict__ refN, const float* __restrict__ lrU,
        int* __restrict__ Sint, float* __restrict__ Sout) {
    __shared__ float aT[KF][64];   // 36864 B
    __shared__ float bT[KF][32];   // 18432 B
    int b  = blockIdx.y;
    int c0 = blockIdx.x * 32;
    int tid = threadIdx.x;
    int tr = tid & 15, tc = tid >> 4;
    const float* refB = refN + b * KF * LP;
    const float* lrB  = lrU  + b * KF * LP;

    for (int i = tid; i < KF * 32; i += 256) {      // 18 iters, coalesced
        int k = i >> 5, c = i & 31;
        bT[k][c] = lrB[k * LP + c0 + c];
    }

    float bv[2] = {-1e30f, -1e30f};
    int   bi[2] = {0, 0};

    for (int r0 = 0; r0 < LP; r0 += 64) {
        __syncthreads();                            // aT reuse + (1st) bT ready
        for (int i = tid; i < KF * 64; i += 256) {  // 36 iters, coalesced
            int k = i >> 6, r = i & 63;
            aT[k][r] = refB[k * LP + r0 + r];
        }
        __syncthreads();

        float acc[4][2];
        #pragma unroll
        for (int i = 0; i < 4; ++i) { acc[i][0] = 0.f; acc[i][1] = 0.f; }

        #pragma unroll 8
        for (int k = 0; k < KF; ++k) {
            const float4 a  = *(const float4*)&aT[k][tr * 4];
            const float2 bb = *(const float2*)&bT[k][tc * 2];
            acc[0][0] = fmaf(a.x, bb.x, acc[0][0]);
            acc[1][0] = fmaf(a.y, bb.x, acc[1][0]);
            acc[2][0] = fmaf(a.z, bb.x, acc[2][0]);
            acc[3][0] = fmaf(a.w, bb.x, acc[3][0]);
            acc[0][1] = fmaf(a.x, bb.y, acc[0][1]);
            acc[1][1] = fmaf(a.y, bb.y, acc[1][1]);
            acc[2][1] = fmaf(a.z, bb.y, acc[2][1]);
            acc[3][1] = fmaf(a.w, bb.y, acc[3][1]);
        }

        #pragma unroll
        for (int j = 0; j < 2; ++j) {
            float v = acc[0][j];
            int ri = r0 + tr * 4;
            #pragma unroll
            for (int i = 1; i < 4; ++i) {           // strict > : first idx wins
                if (acc[i][j] > v) { v = acc[i][j]; ri = r0 + tr * 4 + i; }
            }
            #pragma unroll
            for (int off = 1; off < 16; off <<= 1) {
                float v2 = __shfl_xor(v, off, 64);
                int   r2 = __shfl_xor(ri, off, 64);
                if (v2 > v || (v2 == v && r2 < ri)) { v = v2; ri = r2; }
            }
            if (v > bv[j] || (v == bv[j] && ri < bi[j])) { bv[j] = v; bi[j] = ri; }
        }
    }

    if (tr == 0) {
        #pragma unroll
        for (int j = 0; j < 2; ++j) {
            int col = c0 + tc * 2 + j;
            Sint[b * LP + col] = bi[j];
            Sout[b * LP + col] = (float)bi[j];
        }
    }
}

// ----------------------------------------------------------------- fold ----
// T_org[b,c,y,x] = sum over the <=9 covering 6x6/stride-2 patches (lh,lw) of
// org[b,c, 2*sh+dy-2, 2*sw+dx-2], (sh,sw) from S[b,lh*96+lw],
// dy = y+2-2*lh, dx = x+2-2*lw. Every output written exactly once (no zeroing
// needed, no atomics).
__global__ void k_fold(const float* __restrict__ org, const int* __restrict__ Sint,
                       float* __restrict__ out) {
    int gid = blockIdx.x * blockDim.x + threadIdx.x;
    if (gid >= BATCH * CCH * OH * OW) return;
    int x = gid % OW;
    int t = gid / OW;
    int y = t % OH; t /= OH;
    int c = t % CCH;
    int b = t / CCH;
    const int*   Sb   = Sint + b * LP;
    const float* orgb = org + (b * CCH + c) * OH * OW;
    int lhm = (y + 2) >> 1;
    int lwm = (x + 2) >> 1;
    int lh0 = lhm - 2 > 0 ? lhm - 2 : 0;
    int lh1 = lhm < 95 ? lhm : 95;
    int lw0 = lwm - 2 > 0 ? lwm - 2 : 0;
    int lw1 = lwm < 95 ? lwm : 95;
    float acc = 0.f;
    for (int lh = lh0; lh <= lh1; ++lh) {
        int dy = y + 2 - 2 * lh;
        if (dy > 5) continue;
        for (int lw = lw0; lw <= lw1; ++lw) {
            int dx = x + 2 - 2 * lw;
            if (dx > 5) continue;
            int s  = Sb[lh * 96 + lw];
            int sh = s / 96, sw = s - sh * 96;
            int u = 2 * sh + dy - 2;
            int v = 2 * sw + dx - 2;
            if ((unsigned)u < (unsigned)OH && (unsigned)v < (unsigned)OW)
                acc += orgb[u * OW + v];
        }
    }
    out[gid] = acc;
}

// --------------------------------------------------------------- launch ----
extern "C" void kernel_launch(void* const* d_in, const int* in_sizes, int n_in,
                              void* d_out, int out_size, void* d_ws, size_t ws_size,
                              hipStream_t stream) {
    const float* lrsr = (const float*)d_in[0];
    const float* refsr = (const float*)d_in[1];
    const float* org   = (const float*)d_in[2];
    // scalars d_in[3..6] fixed: k=3, pad=1, stride=1, lv=2 (hardcoded).

    char* ws = (char*)d_ws;
    float* rinv = (float*)ws;                                   // B*LP f32
    int*   Sint = (int*)(ws + (size_t)BATCH * LP * 4);          // B*LP i32
    float* refN = (float*)(ws + (size_t)2 * BATCH * LP * 4);    // B*KF*LP f32
    float* lrU  = refN + (size_t)BATCH * KF * LP;               // B*KF*LP f32

    float* outT = (float*)d_out;                  // 2*16*192*192
    float* outS = outT + (size_t)BATCH * CCH * OH * OW;  // 2*9216 (as f32)

    k_norm<<<(BATCH * LP + 255) / 256, 256, 0, stream>>>(refsr, rinv);
    k_unfold<<<(BATCH * KF * LP + 255) / 256, 256, 0, stream>>>(lrsr, refsr, rinv, refN, lrU);
    k_gemm_argmax<<<dim3(LP / 32, BATCH), 256, 0, stream>>>(refN, lrU, Sint, outS);
    k_fold<<<(BATCH * CCH * OH * OW + 255) / 256, 256, 0, stream>>>(org, Sint, outT);
}

// Round 2
// 718.683 us; speedup vs baseline: 2.6189x; 2.6189x over previous
//
#include <hip/hip_runtime.h>

// SearchTransfer on MI355X — R2: 128x128 block tile, 8x8 per-thread fp32 GEMM,
// persistent blocks + atomic work queue, two-stage argmax.
// B=2, C=16, H=W=96, k=3, pad=1, stride=1, lv=2 (sc=2 -> k2=6,p2=2,s2=2).
// L = 9216, KF = 144. out = [T_org (2*16*192*192), S (2*9216 as f32)]

#define BATCH 2
#define CCH   16
#define HH    96
#define WW    96
#define LP    9216
#define KF    144
#define OH    192
#define OW    192

#define NCB   72        // col-blocks  (9216/128)
#define NRT   72        // row-tiles   (9216/128)
#define NITEMS (BATCH * NRT * NCB)   // 10368
#define KC    48        // K-chunk staged in LDS

// ---------------------------------------------------------------- norms ----
__global__ void k_norm(const float* __restrict__ ref, float* __restrict__ rinv) {
    int gid = blockIdx.x * blockDim.x + threadIdx.x;
    if (gid >= BATCH * LP) return;
    int b = gid / LP, l = gid - b * LP;
    int py = l / WW, px = l - py * WW;
    const float* rb = ref + b * CCH * HH * WW;
    float s = 0.f;
    for (int c = 0; c < CCH; ++c) {
        const float* rc = rb + c * HH * WW;
        #pragma unroll
        for (int dy = 0; dy < 3; ++dy) {
            int y = py + dy - 1;
            if ((unsigned)y >= (unsigned)HH) continue;
            #pragma unroll
            for (int dx = 0; dx < 3; ++dx) {
                int x = px + dx - 1;
                if ((unsigned)x >= (unsigned)WW) continue;
                float v = rc[y * WW + x];
                s += v * v;
            }
        }
    }
    rinv[gid] = 1.f / fmaxf(sqrtf(s), 1e-12f);
}

// --------------------------------------------------------------- unfold ----
// refN normalized; lrU raw (positive per-column scale is argmax-invariant).
__global__ void k_unfold(const float* __restrict__ lr, const float* __restrict__ ref,
                         const float* __restrict__ rinv,
                         float* __restrict__ refN, float* __restrict__ lrU) {
    int gid = blockIdx.x * blockDim.x + threadIdx.x;
    if (gid >= BATCH * KF * LP) return;
    int l = gid % LP;
    int t = gid / LP;
    int f = t % KF;
    int b = t / KF;
    int c = f / 9, r9 = f - c * 9;
    int dy = r9 / 3, dx = r9 - dy * 3;
    int py = l / WW, px = l - py * WW;
    int y = py + dy - 1, x = px + dx - 1;
    bool in = ((unsigned)y < (unsigned)HH) && ((unsigned)x < (unsigned)WW);
    int src = ((b * CCH + c) * HH + y) * WW + x;
    float rv = in ? ref[src] : 0.f;
    float lv = in ? lr[src]  : 0.f;
    refN[gid] = rv * rinv[b * LP + l];
    lrU[gid]  = lv;
}

// ------------------------------------------------------- GEMM + argmax -----
// Persistent blocks pop items from an atomic queue. Item = (b, rowTile, colBlk):
// 128 ref-rows x 128 lr-cols, K=144 in 3 LDS chunks of 48.
// Threads: tid = ct*16 + rt (rt = lane&15). Per-thread 8x8:
//   rows r0 + {rt*4+i, 64+rt*4+i},  cols c0 + {ct*4+j, 64+ct*4+j}.
// LDS reads: 16B/lane stride -> <=2-way bank conflicts (free).
// Partial argmax per item -> pval/pidx[b][rowTile][col]; merged later.
__global__ __launch_bounds__(256) void k_gemm_argmax(
        const float* __restrict__ refN, const float* __restrict__ lrU,
        int* __restrict__ counter,
        float* __restrict__ pval, int* __restrict__ pidx) {
    __shared__ float aT[KC][128];   // 24576 B
    __shared__ float bT[KC][128];   // 24576 B
    __shared__ int s_item;
    int tid = threadIdx.x;
    int rt = tid & 15, ct = tid >> 4;

    for (;;) {
        if (tid == 0) s_item = atomicAdd(counter, 1);
        __syncthreads();
        int item = s_item;
        if (item >= NITEMS) break;

        int b = item / (NRT * NCB);
        int rem = item - b * (NRT * NCB);
        int rowTile = rem / NCB;          // consecutive items sweep colBlk -> A-tile hot in L2/L3
        int colBlk = rem - rowTile * NCB;
        int r0 = rowTile * 128, c0 = colBlk * 128;
        const float* refB = refN + (size_t)b * KF * LP;
        const float* lrB  = lrU  + (size_t)b * KF * LP;

        float acc[8][8];
        #pragma unroll
        for (int i = 0; i < 8; ++i)
            #pragma unroll
            for (int j = 0; j < 8; ++j) acc[i][j] = 0.f;

        for (int kc0 = 0; kc0 < KF; kc0 += KC) {
            __syncthreads();   // LDS reuse safe (also separates s_item read from next write)
            // stage: 48x128 each, 6 float4 per thread per matrix, fully coalesced
            #pragma unroll
            for (int i = 0; i < 6; ++i) {
                int e = (tid + i * 256) * 4;        // element 0..6143
                int kk = e >> 7, r = e & 127;
                *(float4*)&aT[kk][r] = *(const float4*)&refB[(size_t)(kc0 + kk) * LP + r0 + r];
                *(float4*)&bT[kk][r] = *(const float4*)&lrB [(size_t)(kc0 + kk) * LP + c0 + r];
            }
            __syncthreads();

            #pragma unroll 2
            for (int kk = 0; kk < KC; ++kk) {
                float4 a0 = *(const float4*)&aT[kk][rt * 4];
                float4 a1 = *(const float4*)&aT[kk][64 + rt * 4];
                float4 b0 = *(const float4*)&bT[kk][ct * 4];
                float4 b1 = *(const float4*)&bT[kk][64 + ct * 4];
                float av[8] = {a0.x, a0.y, a0.z, a0.w, a1.x, a1.y, a1.z, a1.w};
                float bv[8] = {b0.x, b0.y, b0.z, b0.w, b1.x, b1.y, b1.z, b1.w};
                #pragma unroll
                for (int i = 0; i < 8; ++i)
                    #pragma unroll
                    for (int j = 0; j < 8; ++j)
                        acc[i][j] = fmaf(av[i], bv[j], acc[i][j]);
            }
        }

        // per-thread fold over 8 rows (ascending global row, strict > = first wins)
        #pragma unroll
        for (int j = 0; j < 8; ++j) {
            float v = acc[0][j];
            int ri = r0 + rt * 4;
            #pragma unroll
            for (int i = 1; i < 8; ++i) {
                int rr = r0 + (i < 4 ? rt * 4 + i : 64 + rt * 4 + (i - 4));
                if (acc[i][j] > v) { v = acc[i][j]; ri = rr; }
            }
            // reduce across rt (lanes xor 1,2,4,8 inside 16-lane groups)
            #pragma unroll
            for (int off = 1; off < 16; off <<= 1) {
                float v2 = __shfl_xor(v, off, 64);
                int   r2 = __shfl_xor(ri, off, 64);
                if (v2 > v || (v2 == v && r2 < ri)) { v = v2; ri = r2; }
            }
            if (rt == 0) {
                int col = c0 + (j < 4 ? ct * 4 + j : 64 + ct * 4 + (j - 4));
                size_t o = ((size_t)b * NRT + rowTile) * LP + col;
                pval[o] = v;
                pidx[o] = ri;
            }
        }
        __syncthreads();   // everyone done reading s_item & LDS before next pop
    }
}

// -------------------------------------------------------- argmax merge -----
__global__ void k_merge(const float* __restrict__ pval, const int* __restrict__ pidx,
                        int* __restrict__ Sint, float* __restrict__ Sout) {
    int gid = blockIdx.x * blockDim.x + threadIdx.x;
    if (gid >= BATCH * LP) return;
    int b = gid / LP, l = gid - b * LP;
    float bv = -1e30f; int bi = 0;
    for (int rc = 0; rc < NRT; ++rc) {           // ascending rows -> first-wins on ties
        size_t o = ((size_t)b * NRT + rc) * LP + l;
        float v = pval[o];
        if (v > bv) { bv = v; bi = pidx[o]; }
    }
    Sint[gid] = bi;
    Sout[gid] = (float)bi;
}

// ----------------------------------------------------------------- fold ----
__global__ void k_fold(const float* __restrict__ org, const int* __restrict__ Sint,
                       float* __restrict__ out) {
    int gid = blockIdx.x * blockDim.x + threadIdx.x;
    if (gid >= BATCH * CCH * OH * OW) return;
    int x = gid % OW;
    int t = gid / OW;
    int y = t % OH; t /= OH;
    int c = t % CCH;
    int b = t / CCH;
    const int*   Sb   = Sint + b * LP;
    const float* orgb = org + (b * CCH + c) * OH * OW;
    int lhm = (y + 2) >> 1;
    int lwm = (x + 2) >> 1;
    int lh0 = lhm - 2 > 0 ? lhm - 2 : 0;
    int lh1 = lhm < 95 ? lhm : 95;
    int lw0 = lwm - 2 > 0 ? lwm - 2 : 0;
    int lw1 = lwm < 95 ? lwm : 95;
    float acc = 0.f;
    for (int lh = lh0; lh <= lh1; ++lh) {
        int dy = y + 2 - 2 * lh;
        if (dy > 5) continue;
        for (int lw = lw0; lw <= lw1; ++lw) {
            int dx = x + 2 - 2 * lw;
            if (dx > 5) continue;
            int s  = Sb[lh * 96 + lw];
            int sh = s / 96, sw = s - sh * 96;
            int u = 2 * sh + dy - 2;
            int v = 2 * sw + dx - 2;
            if ((unsigned)u < (unsigned)OH && (unsigned)v < (unsigned)OW)
                acc += orgb[u * OW + v];
        }
    }
    out[gid] = acc;
}

// --------------------------------------------------------------- launch ----
extern "C" void kernel_launch(void* const* d_in, const int* in_sizes, int n_in,
                              void* d_out, int out_size, void* d_ws, size_t ws_size,
                              hipStream_t stream) {
    const float* lrsr = (const float*)d_in[0];
    const float* refsr = (const float*)d_in[1];
    const float* org   = (const float*)d_in[2];

    char* ws = (char*)d_ws;
    size_t off = 0;
    int* counter = (int*)(ws + off);                 off += 256;
    float* rinv  = (float*)(ws + off);               off += (size_t)BATCH * LP * 4;
    int*   Sint  = (int*)(ws + off);                 off += (size_t)BATCH * LP * 4;
    float* pval  = (float*)(ws + off);               off += (size_t)BATCH * NRT * LP * 4;
    int*   pidx  = (int*)(ws + off);                 off += (size_t)BATCH * NRT * LP * 4;
    float* refN  = (float*)(ws + off);               off += (size_t)BATCH * KF * LP * 4;
    float* lrU   = (float*)(ws + off);               off += (size_t)BATCH * KF * LP * 4;

    float* outT = (float*)d_out;                          // 2*16*192*192
    float* outS = outT + (size_t)BATCH * CCH * OH * OW;   // 2*9216 (as f32)

    hipMemsetAsync(counter, 0, sizeof(int), stream);
    k_norm<<<(BATCH * LP + 255) / 256, 256, 0, stream>>>(refsr, rinv);
    k_unfold<<<(BATCH * KF * LP + 255) / 256, 256, 0, stream>>>(lrsr, refsr, rinv, refN, lrU);
    k_gemm_argmax<<<768, 256, 0, stream>>>(refN, lrU, counter, pval, pidx);
    k_merge<<<(BATCH * LP + 255) / 256, 256, 0, stream>>>(pval, pidx, Sint, outS);
    k_fold<<<(BATCH * CCH * OH * OW + 255) / 256, 256, 0, stream>>>(org, Sint, outT);
}